// Round 3
// baseline (753.482 us; speedup 1.0000x reference)
//
#include <hip/hip_runtime.h>
#include <stdint.h>

typedef __bf16 bf16;
typedef __attribute__((ext_vector_type(8))) __bf16 bf16x8;
typedef __attribute__((ext_vector_type(4))) __bf16 bf16x4;
typedef __attribute__((ext_vector_type(4))) float f32x4;

#define DEVFN static __device__ __forceinline__

DEVFN void gload16(const bf16* g, char* l) {
  __builtin_amdgcn_global_load_lds(
      (const __attribute__((address_space(1))) void*)g,
      (__attribute__((address_space(3))) void*)l, 16, 0, 0);
}

DEVFN int swz(int row, int kb) { return row * 128 + (kb ^ ((row & 7) << 4)); }

DEVFN float redmax16(float v) {
  v = fmaxf(v, __shfl_xor(v, 1));
  v = fmaxf(v, __shfl_xor(v, 2));
  v = fmaxf(v, __shfl_xor(v, 4));
  v = fmaxf(v, __shfl_xor(v, 8));
  return v;
}

// ---------------- prep: fp32 -> bf16 + weight transposes --------------------
__global__ __launch_bounds__(256) void prep_kernel(
    const float* __restrict__ x, const float* __restrict__ Wq,
    const float* __restrict__ Wk, const float* __restrict__ Wv,
    const float* __restrict__ Wp, bf16* __restrict__ xb,
    bf16* __restrict__ Wt, bf16* __restrict__ Wpt) {
  const int64_t tid = blockIdx.x * 256LL + threadIdx.x;
  const int64_t stride = (int64_t)gridDim.x * 256LL;
  for (int64_t i = tid; i < (8192LL * 512) / 4; i += stride) {
    float4 v = ((const float4*)x)[i];
    bf16x4 o = {(bf16)v.x, (bf16)v.y, (bf16)v.z, (bf16)v.w};
    ((bf16x4*)xb)[i] = o;
  }
  for (int64_t i = tid; i < 1536LL * 512; i += stride) {
    int c = (int)(i >> 9), k = (int)(i & 511);
    int wsel = c >> 9, cc = c & 511;
    const float* W = wsel == 0 ? Wq : (wsel == 1 ? Wk : Wv);
    Wt[i] = (bf16)W[k * 512 + cc];
  }
  for (int64_t i = tid; i < 512LL * 512; i += stride) {
    int c = (int)(i >> 9), k = (int)(i & 511);
    Wpt[i] = (bf16)Wp[k * 512 + c];
  }
}

// ---------------- shared 128x128 bf16 GEMM mainloop (K=512, BK=64) ----------
DEVFN void gemm_main(const bf16* __restrict__ A, const bf16* __restrict__ B,
                     int rowA0, int rowB0, char* sA, char* sB, f32x4 acc[4][4],
                     int wr, int wc, int lane, int w) {
#pragma unroll
  for (int m = 0; m < 4; m++)
#pragma unroll
    for (int n = 0; n < 4; n++) acc[m][n] = (f32x4){0.f, 0.f, 0.f, 0.f};
  const int lr = lane >> 3;
  const int kswz = 8 * ((lane & 7) ^ lr);
  for (int k0 = 0; k0 < 512; k0 += 64) {
#pragma unroll
    for (int j = 0; j < 4; j++) {
      const int c = w * 4 + j;
      gload16(A + (rowA0 + c * 8 + lr) * 512 + k0 + kswz, sA + c * 1024);
      gload16(B + (rowB0 + c * 8 + lr) * 512 + k0 + kswz, sB + c * 1024);
    }
    __syncthreads();
    bf16x8 af[4][2], bfv[4][2];
#pragma unroll
    for (int m = 0; m < 4; m++)
#pragma unroll
      for (int kk = 0; kk < 2; kk++) {
        af[m][kk] = *(const bf16x8*)(sA + swz(wr * 64 + m * 16 + (lane & 15),
                                              kk * 64 + (lane >> 4) * 16));
        bfv[m][kk] = *(const bf16x8*)(sB + swz(wc * 64 + m * 16 + (lane & 15),
                                               kk * 64 + (lane >> 4) * 16));
      }
#pragma unroll
    for (int m = 0; m < 4; m++)
#pragma unroll
      for (int n = 0; n < 4; n++)
#pragma unroll
        for (int kk = 0; kk < 2; kk++)
          acc[m][n] = __builtin_amdgcn_mfma_f32_16x16x32_bf16(
              af[m][kk], bfv[n][kk], acc[m][n], 0, 0, 0);
    __syncthreads();
  }
}

// ---------------- QKV projection ------------------------------------------
__global__ __launch_bounds__(256) void qkv_gemm(
    const bf16* __restrict__ xb, const bf16* __restrict__ Wt,
    const float* __restrict__ bq, const float* __restrict__ bk,
    const float* __restrict__ bv, bf16* __restrict__ Qb, bf16* __restrict__ Kb,
    bf16* __restrict__ Vt) {
  __shared__ __align__(128) char sA[16384];
  __shared__ __align__(128) char sB[16384];
  const int lane = threadIdx.x & 63, w = threadIdx.x >> 6;
  const int wr = w >> 1, wc = w & 1;
  const int rowA0 = blockIdx.y * 128;
  const int colB0 = blockIdx.x * 128;
  f32x4 acc[4][4];
  gemm_main(xb, Wt, rowA0, colB0, sA, sB, acc, wr, wc, lane, w);
  const int which = colB0 >> 9;
  const int cc0 = colB0 & 511;
  const float* bias = which == 0 ? bq : (which == 1 ? bk : bv);
#pragma unroll
  for (int m = 0; m < 4; m++)
#pragma unroll
    for (int n = 0; n < 4; n++)
#pragma unroll
      for (int r = 0; r < 4; r++) {
        int row = rowA0 + wr * 64 + m * 16 + (lane >> 4) * 4 + r;
        int col = cc0 + wc * 64 + n * 16 + (lane & 15);
        float v = acc[m][n][r] + bias[col];
        if (which == 0) {
          Qb[(int64_t)row * 512 + col] = (bf16)v;
        } else if (which == 1) {
          Kb[(int64_t)row * 512 + col] = (bf16)v;
        } else {
          int b = row >> 12, nn = row & 4095;
          int hh = col >> 6, e = col & 63;
          Vt[(((int64_t)(b * 8 + hh)) * 64 + e) * 4096 + nn] = (bf16)v;
        }
      }
}

// ---------------- output projection (fp32 out) ----------------------------
__global__ __launch_bounds__(256) void out_gemm(const bf16* __restrict__ Ob,
                                                const bf16* __restrict__ Wpt,
                                                const float* __restrict__ bp,
                                                float* __restrict__ out) {
  __shared__ __align__(128) char sA[16384];
  __shared__ __align__(128) char sB[16384];
  const int lane = threadIdx.x & 63, w = threadIdx.x >> 6;
  const int wr = w >> 1, wc = w & 1;
  const int rowA0 = blockIdx.y * 128;
  const int colB0 = blockIdx.x * 128;
  f32x4 acc[4][4];
  gemm_main(Ob, Wpt, rowA0, colB0, sA, sB, acc, wr, wc, lane, w);
#pragma unroll
  for (int m = 0; m < 4; m++)
#pragma unroll
    for (int n = 0; n < 4; n++)
#pragma unroll
      for (int r = 0; r < 4; r++) {
        int row = rowA0 + wr * 64 + m * 16 + (lane >> 4) * 4 + r;
        int col = colB0 + wc * 64 + n * 16 + (lane & 15);
        out[(int64_t)row * 512 + col] = acc[m][n][r] + bp[col];
      }
}

// ---------------- fused flash attention, multi-head dist sharing -----------
// grid (256 qtiles of 16, 2 b, 2 hg), 256 thr = 4 waves = 4 heads.
// dist tile: [64 col][16 row] f32, 4-row-block XOR swizzle, 3-buffer ring.
__global__ __launch_bounds__(256, 4) void attn_kernel(
    const bf16* __restrict__ Qb, const bf16* __restrict__ Kb,
    const bf16* __restrict__ Vt, const float* __restrict__ coords,
    const float* __restrict__ slopes, bf16* __restrict__ Ob) {
  __shared__ float sdist[3][1024];             // 12 KB
  __shared__ __align__(128) char sP[4][2048];  // 8 KB

  const int tid = threadIdx.x;
  const int lane = tid & 63, w = tid >> 6;
  const int c = lane & 15, g = lane >> 4;
  const int b = blockIdx.y;
  const int h = blockIdx.z * 4 + w;
  const int q0 = blockIdx.x * 16;

  const float LOG2E = 1.4426950408889634f;
  const float c1 = 0.125f * LOG2E;
  const float negsl2 = -slopes[h] * LOG2E;

  // Q fragments in registers for the whole kernel (16 q-rows per wave)
  bf16x8 aq[2];
  {
    int64_t base = ((int64_t)(b * 4096 + q0 + c)) * 512 + h * 64 + g * 8;
    aq[0] = *(const bf16x8*)(Qb + base);
    aq[1] = *(const bf16x8*)(Qb + base + 32);
  }

  // producer: thread handles col pcol, row-block prblk (rows prblk*4..+3)
  const int pcol = tid & 63, prblk = tid >> 6;
  const float2* cb2 = (const float2*)coords + (int64_t)b * 4096;
  float qpx[4], qpy[4];
#pragma unroll
  for (int j = 0; j < 4; j++) {
    float2 c2 = cb2[q0 + prblk * 4 + j];
    qpx[j] = c2.x;
    qpy[j] = c2.y;
  }
  const int pidx = pcol * 16 + ((prblk ^ ((pcol >> 1) & 3)) << 2);

  bf16x8 ones;
#pragma unroll
  for (int j = 0; j < 8; j++) ones[j] = (bf16)1.0f;

  float m2[4];
  f32x4 o[4], osum;
#pragma unroll
  for (int r = 0; r < 4; r++) m2[r] = -1e30f;
#pragma unroll
  for (int n = 0; n < 4; n++) o[n] = (f32x4){0.f, 0.f, 0.f, 0.f};
  osum = (f32x4){0.f, 0.f, 0.f, 0.f};

  const bf16* Kp = Kb + (int64_t)b * 4096 * 512 + h * 64;
  const bf16* Vp = Vt + (int64_t)(b * 8 + h) * 64 * 4096;

  bf16x8 kf[4][2], vf[4][2];
#define LOADK(KV)                                                         \
  {                                                                       \
    _Pragma("unroll") for (int t = 0; t < 4; t++) _Pragma("unroll") for ( \
        int kk = 0; kk < 2; kk++) kf[t][kk] =                             \
        *(const bf16x8*)(Kp + (int)(((KV) + t * 16 + c) * 512 +           \
                                    kk * 32 + g * 8));                    \
  }
#define LOADV(KV)                                                         \
  {                                                                       \
    _Pragma("unroll") for (int n = 0; n < 4; n++) _Pragma("unroll") for ( \
        int kk = 0; kk < 2; kk++) vf[n][kk] =                             \
        *(const bf16x8*)(Vp + (int)((n * 16 + c) * 4096 + (KV) +          \
                                    kk * 32 + g * 8));                    \
  }

#define PRODUCE(BUF, KC)                                            \
  {                                                                 \
    float d0, d1, d2, d3;                                           \
    float dx, dy;                                                   \
    dx = qpx[0] - (KC).x; dy = qpy[0] - (KC).y;                     \
    d0 = __builtin_amdgcn_sqrtf(dx * dx + dy * dy);                 \
    dx = qpx[1] - (KC).x; dy = qpy[1] - (KC).y;                     \
    d1 = __builtin_amdgcn_sqrtf(dx * dx + dy * dy);                 \
    dx = qpx[2] - (KC).x; dy = qpy[2] - (KC).y;                     \
    d2 = __builtin_amdgcn_sqrtf(dx * dx + dy * dy);                 \
    dx = qpx[3] - (KC).x; dy = qpy[3] - (KC).y;                     \
    d3 = __builtin_amdgcn_sqrtf(dx * dx + dy * dy);                 \
    *(f32x4*)(&sdist[BUF][pidx]) = (f32x4){d0, d1, d2, d3};         \
  }

  // prologue
  LOADK(0);
  LOADV(0);
  float2 kcA = cb2[pcol];  // tile 0 coords
  PRODUCE(0, kcA);
  kcA = cb2[64 + pcol];  // tile 1 coords

  char* pw = (char*)sP[w];
  int cb = 0;
  for (int i = 0; i < 64; i++) {
    int nb = cb + 1;
    if (nb == 3) nb = 0;
    if (i + 1 < 64) PRODUCE(nb, kcA);
    if (i + 2 < 64) kcA = cb2[(i + 2) * 64 + pcol];
    __syncthreads();
    const float* db = sdist[cb];

    // S = QK^T * c1 - slope*log2e*dist
    float s[4][4];
#pragma unroll
    for (int t = 0; t < 4; t++) {
      f32x4 sa = (f32x4){0.f, 0.f, 0.f, 0.f};
      sa = __builtin_amdgcn_mfma_f32_16x16x32_bf16(aq[0], kf[t][0], sa, 0, 0, 0);
      sa = __builtin_amdgcn_mfma_f32_16x16x32_bf16(aq[1], kf[t][1], sa, 0, 0, 0);
      const int col = t * 16 + c;
      f32x4 dv = *(const f32x4*)(&db[col * 16 + ((g ^ ((col >> 1) & 3)) << 2)]);
#pragma unroll
      for (int r = 0; r < 4; r++)
        s[t][r] = __builtin_fmaf(sa[r], c1, dv[r] * negsl2);
    }
    if (i + 1 < 64) LOADK((i + 1) * 64);

    // defer-max online softmax (THR = 8 in base-2)
    float lm[4];
#pragma unroll
    for (int r = 0; r < 4; r++)
      lm[r] = fmaxf(fmaxf(s[0][r], s[1][r]), fmaxf(s[2][r], s[3][r]));
    bool ex = lm[0] > m2[0] + 8.f || lm[1] > m2[1] + 8.f ||
              lm[2] > m2[2] + 8.f || lm[3] > m2[3] + 8.f;
    if (__any(ex)) {
#pragma unroll
      for (int r = 0; r < 4; r++) {
        float pm = redmax16(lm[r]);
        float nm = fmaxf(m2[r], pm);
        float sc = __builtin_amdgcn_exp2f(m2[r] - nm);
        m2[r] = nm;
#pragma unroll
        for (int n = 0; n < 4; n++) o[n][r] *= sc;
        osum[r] *= sc;
      }
    }

    // P = exp2(s - m2) -> per-wave LDS (swizzled), read back as A-fragments
#pragma unroll
    for (int t = 0; t < 4; t++)
#pragma unroll
      for (int r = 0; r < 4; r++) {
        float p = __builtin_amdgcn_exp2f(s[t][r] - m2[r]);
        int row = g * 4 + r;
        *(bf16*)(pw + row * 128 + ((t * 32 + c * 2) ^ ((row & 7) << 4))) =
            (bf16)p;
      }
    bf16x8 pa0 = *(const bf16x8*)(pw + c * 128 + ((g * 16) ^ ((c & 7) << 4)));
    bf16x8 pa1 =
        *(const bf16x8*)(pw + c * 128 + ((64 + g * 16) ^ ((c & 7) << 4)));
#pragma unroll
    for (int n = 0; n < 4; n++) {
      o[n] = __builtin_amdgcn_mfma_f32_16x16x32_bf16(pa0, vf[n][0], o[n], 0, 0, 0);
      o[n] = __builtin_amdgcn_mfma_f32_16x16x32_bf16(pa1, vf[n][1], o[n], 0, 0, 0);
    }
    osum = __builtin_amdgcn_mfma_f32_16x16x32_bf16(pa0, ones, osum, 0, 0, 0);
    osum = __builtin_amdgcn_mfma_f32_16x16x32_bf16(pa1, ones, osum, 0, 0, 0);
    if (i + 1 < 64) LOADV((i + 1) * 64);
    cb = nb;
  }

  // epilogue: normalize and store attention output in [b,n,d] bf16
#pragma unroll
  for (int r = 0; r < 4; r++) {
    float inv = 1.f / osum[r];
    int64_t row = (int64_t)b * 4096 + q0 + g * 4 + r;
#pragma unroll
    for (int n = 0; n < 4; n++)
      Ob[row * 512 + h * 64 + n * 16 + c] = (bf16)(o[n][r] * inv);
  }
}

// ---------------- launch ---------------------------------------------------
extern "C" void kernel_launch(void* const* d_in, const int* in_sizes, int n_in,
                              void* d_out, int out_size, void* d_ws,
                              size_t ws_size, hipStream_t stream) {
  const float* x = (const float*)d_in[0];
  const float* coords = (const float*)d_in[1];
  const float* Wq = (const float*)d_in[2];
  const float* bq = (const float*)d_in[3];
  const float* Wk = (const float*)d_in[4];
  const float* bk = (const float*)d_in[5];
  const float* Wv = (const float*)d_in[6];
  const float* bv = (const float*)d_in[7];
  const float* Wp = (const float*)d_in[8];
  const float* bp = (const float*)d_in[9];
  const float* slopes = (const float*)d_in[10];

  char* ws = (char*)d_ws;
  bf16* xb = (bf16*)(ws);
  bf16* Wt = (bf16*)(ws + 8388608);
  bf16* Wpt = (bf16*)(ws + 9961472);
  bf16* Qb = (bf16*)(ws + 10485760);
  bf16* Kb = (bf16*)(ws + 18874368);
  bf16* Vt = (bf16*)(ws + 27262976);
  bf16* Ob = (bf16*)(ws + 35651584);

  hipLaunchKernelGGL(prep_kernel, dim3(1024), dim3(256), 0, stream, x, Wq, Wk,
                     Wv, Wp, xb, Wt, Wpt);
  hipLaunchKernelGGL(qkv_gemm, dim3(12, 64), dim3(256), 0, stream, xb, Wt, bq,
                     bk, bv, Qb, Kb, Vt);
  hipLaunchKernelGGL(attn_kernel, dim3(256, 2, 2), dim3(256), 0, stream, Qb,
                     Kb, Vt, coords, slopes, Ob);
  hipLaunchKernelGGL(out_gemm, dim3(4, 64), dim3(256), 0, stream, Ob, Wpt, bp,
                     (float*)d_out);
}

// Round 4
// 576.050 us; speedup vs baseline: 1.3080x; 1.3080x over previous
//
#include <hip/hip_runtime.h>
#include <stdint.h>

typedef __bf16 bf16;
typedef __attribute__((ext_vector_type(8))) __bf16 bf16x8;
typedef __attribute__((ext_vector_type(4))) __bf16 bf16x4;
typedef __attribute__((ext_vector_type(4))) float f32x4;

#define DEVFN static __device__ __forceinline__

DEVFN void gload16(const bf16* g, char* l) {
  __builtin_amdgcn_global_load_lds(
      (const __attribute__((address_space(1))) void*)g,
      (__attribute__((address_space(3))) void*)l, 16, 0, 0);
}

DEVFN int swz(int row, int kb) { return row * 128 + (kb ^ ((row & 7) << 4)); }

// ---------------- prep: fp32 -> bf16 + weight transposes --------------------
__global__ __launch_bounds__(256) void prep_kernel(
    const float* __restrict__ x, const float* __restrict__ Wq,
    const float* __restrict__ Wk, const float* __restrict__ Wv,
    const float* __restrict__ Wp, bf16* __restrict__ xb,
    bf16* __restrict__ Wt, bf16* __restrict__ Wpt) {
  const int64_t tid = blockIdx.x * 256LL + threadIdx.x;
  const int64_t stride = (int64_t)gridDim.x * 256LL;
  for (int64_t i = tid; i < (8192LL * 512) / 4; i += stride) {
    float4 v = ((const float4*)x)[i];
    bf16x4 o = {(bf16)v.x, (bf16)v.y, (bf16)v.z, (bf16)v.w};
    ((bf16x4*)xb)[i] = o;
  }
  for (int64_t i = tid; i < 1536LL * 512; i += stride) {
    int c = (int)(i >> 9), k = (int)(i & 511);
    int wsel = c >> 9, cc = c & 511;
    const float* W = wsel == 0 ? Wq : (wsel == 1 ? Wk : Wv);
    Wt[i] = (bf16)W[k * 512 + cc];
  }
  for (int64_t i = tid; i < 512LL * 512; i += stride) {
    int c = (int)(i >> 9), k = (int)(i & 511);
    Wpt[i] = (bf16)Wp[k * 512 + c];
  }
}

// ---------------- shared 128x128 bf16 GEMM mainloop (K=512, BK=64) ----------
DEVFN void gemm_main(const bf16* __restrict__ A, const bf16* __restrict__ B,
                     int rowA0, int rowB0, char* sA, char* sB, f32x4 acc[4][4],
                     int wr, int wc, int lane, int w) {
#pragma unroll
  for (int m = 0; m < 4; m++)
#pragma unroll
    for (int n = 0; n < 4; n++) acc[m][n] = (f32x4){0.f, 0.f, 0.f, 0.f};
  const int lr = lane >> 3;
  const int kswz = 8 * ((lane & 7) ^ lr);
  for (int k0 = 0; k0 < 512; k0 += 64) {
#pragma unroll
    for (int j = 0; j < 4; j++) {
      const int c = w * 4 + j;
      gload16(A + (rowA0 + c * 8 + lr) * 512 + k0 + kswz, sA + c * 1024);
      gload16(B + (rowB0 + c * 8 + lr) * 512 + k0 + kswz, sB + c * 1024);
    }
    __syncthreads();
    bf16x8 af[4][2], bfv[4][2];
#pragma unroll
    for (int m = 0; m < 4; m++)
#pragma unroll
      for (int kk = 0; kk < 2; kk++) {
        af[m][kk] = *(const bf16x8*)(sA + swz(wr * 64 + m * 16 + (lane & 15),
                                              kk * 64 + (lane >> 4) * 16));
        bfv[m][kk] = *(const bf16x8*)(sB + swz(wc * 64 + m * 16 + (lane & 15),
                                               kk * 64 + (lane >> 4) * 16));
      }
#pragma unroll
    for (int m = 0; m < 4; m++)
#pragma unroll
      for (int n = 0; n < 4; n++)
#pragma unroll
        for (int kk = 0; kk < 2; kk++)
          acc[m][n] = __builtin_amdgcn_mfma_f32_16x16x32_bf16(
              af[m][kk], bfv[n][kk], acc[m][n], 0, 0, 0);
    __syncthreads();
  }
}

// ---------------- QKV projection ------------------------------------------
__global__ __launch_bounds__(256) void qkv_gemm(
    const bf16* __restrict__ xb, const bf16* __restrict__ Wt,
    const float* __restrict__ bq, const float* __restrict__ bk,
    const float* __restrict__ bv, bf16* __restrict__ Qb, bf16* __restrict__ Kb,
    bf16* __restrict__ Vt) {
  __shared__ __align__(128) char sA[16384];
  __shared__ __align__(128) char sB[16384];
  const int lane = threadIdx.x & 63, w = threadIdx.x >> 6;
  const int wr = w >> 1, wc = w & 1;
  const int rowA0 = blockIdx.y * 128;
  const int colB0 = blockIdx.x * 128;
  f32x4 acc[4][4];
  gemm_main(xb, Wt, rowA0, colB0, sA, sB, acc, wr, wc, lane, w);
  const int which = colB0 >> 9;
  const int cc0 = colB0 & 511;
  const float* bias = which == 0 ? bq : (which == 1 ? bk : bv);
#pragma unroll
  for (int m = 0; m < 4; m++)
#pragma unroll
    for (int n = 0; n < 4; n++)
#pragma unroll
      for (int r = 0; r < 4; r++) {
        int row = rowA0 + wr * 64 + m * 16 + (lane >> 4) * 4 + r;
        int col = cc0 + wc * 64 + n * 16 + (lane & 15);
        float v = acc[m][n][r] + bias[col];
        if (which == 0) {
          Qb[(int64_t)row * 512 + col] = (bf16)v;
        } else if (which == 1) {
          Kb[(int64_t)row * 512 + col] = (bf16)v;
        } else {
          int b = row >> 12, nn = row & 4095;
          int hh = col >> 6, e = col & 63;
          Vt[(((int64_t)(b * 8 + hh)) * 64 + e) * 4096 + nn] = (bf16)v;
        }
      }
}

// ---------------- output projection (fp32 out) ----------------------------
__global__ __launch_bounds__(256) void out_gemm(const bf16* __restrict__ Ob,
                                                const bf16* __restrict__ Wpt,
                                                const float* __restrict__ bp,
                                                float* __restrict__ out) {
  __shared__ __align__(128) char sA[16384];
  __shared__ __align__(128) char sB[16384];
  const int lane = threadIdx.x & 63, w = threadIdx.x >> 6;
  const int wr = w >> 1, wc = w & 1;
  const int rowA0 = blockIdx.y * 128;
  const int colB0 = blockIdx.x * 128;
  f32x4 acc[4][4];
  gemm_main(Ob, Wpt, rowA0, colB0, sA, sB, acc, wr, wc, lane, w);
#pragma unroll
  for (int m = 0; m < 4; m++)
#pragma unroll
    for (int n = 0; n < 4; n++)
#pragma unroll
      for (int r = 0; r < 4; r++) {
        int row = rowA0 + wr * 64 + m * 16 + (lane >> 4) * 4 + r;
        int col = colB0 + wc * 64 + n * 16 + (lane & 15);
        out[(int64_t)row * 512 + col] = acc[m][n][r] + bp[col];
      }
}

// ---------------- fused flash attention, swapped-QK^T form -----------------
// grid (256 qtiles of 16, 2 b, 2 hg), 256 thr = 4 waves = 4 heads.
// S computed as mfma(K,Q) -> S[kv][q], q = lane&15: P pack is vectorized
// (4x ds_write_b64 + 2x ds_read_b128), row-max = 2 shfl_xor (deferred).
// dist tile [16 q][64 kv] f32, f32x4 granules, 16B XOR swizzle, 3-buf ring.
__global__ __launch_bounds__(256) void attn_kernel(
    const bf16* __restrict__ Qb, const bf16* __restrict__ Kb,
    const bf16* __restrict__ Vt, const float* __restrict__ coords,
    const float* __restrict__ slopes, bf16* __restrict__ Ob) {
  __shared__ float sdist[3][1024];             // 12 KB
  __shared__ __align__(128) char sP[4][2048];  // 8 KB, per-wave

  const int tid = threadIdx.x;
  const int lane = tid & 63, w = tid >> 6;
  const int c = lane & 15, g = lane >> 4;
  const int b = blockIdx.y;
  const int h = blockIdx.z * 4 + w;
  const int q0 = blockIdx.x * 16;

  const float LOG2E = 1.4426950408889634f;
  const float c1 = 0.125f * LOG2E;
  const float negsl2 = -slopes[h] * LOG2E;

  // Q fragments (B-operand of swapped QK^T): lane holds Q[q=c][hd=g*8+j]
  bf16x8 aq[2];
  {
    int64_t base = ((int64_t)(b * 4096 + q0 + c)) * 512 + h * 64 + g * 8;
    aq[0] = *(const bf16x8*)(Qb + base);
    aq[1] = *(const bf16x8*)(Qb + base + 32);
  }

  // producer: thread handles q-row pq, kv-group pkb (4 kv), f32x4 granule
  const int pq = tid & 15, pkb = tid >> 4;
  const float2* cb2 = (const float2*)coords + (int64_t)b * 4096;
  float qcx, qcy;
  {
    float2 qc = cb2[q0 + pq];
    qcx = qc.x;
    qcy = qc.y;
  }
  const int pdst = pq * 256 + ((pkb * 16) ^ ((pq & 7) << 4));  // bytes

  bf16x8 ones;
#pragma unroll
  for (int j = 0; j < 8; j++) ones[j] = (bf16)1.0f;

  float m2 = -1e30f;  // running max for q=c (one row per lane)
  f32x4 o[4], osum;
#pragma unroll
  for (int n = 0; n < 4; n++) o[n] = (f32x4){0.f, 0.f, 0.f, 0.f};
  osum = (f32x4){0.f, 0.f, 0.f, 0.f};

  const bf16* Kp = Kb + (int64_t)b * 4096 * 512 + h * 64;
  const bf16* Vp = Vt + (int64_t)(b * 8 + h) * 64 * 4096;

  bf16x8 kf[4][2], vf[4][2];
#define LOADK(KV)                                                         \
  {                                                                       \
    _Pragma("unroll") for (int t = 0; t < 4; t++) _Pragma("unroll") for ( \
        int kk = 0; kk < 2; kk++) kf[t][kk] =                             \
        *(const bf16x8*)(Kp + (int)(((KV) + t * 16 + c) * 512 +           \
                                    kk * 32 + g * 8));                    \
  }
#define LOADV(KV)                                                         \
  {                                                                       \
    _Pragma("unroll") for (int n = 0; n < 4; n++) _Pragma("unroll") for ( \
        int kk = 0; kk < 2; kk++) vf[n][kk] =                             \
        *(const bf16x8*)(Vp + (int)((n * 16 + c) * 4096 + (KV) +          \
                                    kk * 32 + g * 8));                    \
  }

  auto produce = [&](int buf, float4 A, float4 B) {
    float dx, dy, d0, d1, d2, d3;
    dx = qcx - A.x; dy = qcy - A.y;
    d0 = __builtin_amdgcn_sqrtf(dx * dx + dy * dy);
    dx = qcx - A.z; dy = qcy - A.w;
    d1 = __builtin_amdgcn_sqrtf(dx * dx + dy * dy);
    dx = qcx - B.x; dy = qcy - B.y;
    d2 = __builtin_amdgcn_sqrtf(dx * dx + dy * dy);
    dx = qcx - B.z; dy = qcy - B.w;
    d3 = __builtin_amdgcn_sqrtf(dx * dx + dy * dy);
    *(f32x4*)((char*)sdist[buf] + pdst) = (f32x4){d0, d1, d2, d3};
  };

  // prologue: tile 0 staged, tile-1 coords prefetched
  LOADK(0);
  LOADV(0);
  float4 kca = *(const float4*)(cb2 + pkb * 4);
  float4 kcb = *(const float4*)(cb2 + pkb * 4 + 2);
  produce(0, kca, kcb);
  kca = *(const float4*)(cb2 + 64 + pkb * 4);
  kcb = *(const float4*)(cb2 + 64 + pkb * 4 + 2);

  char* pw = (char*)sP[w];
  const int pmask = (c & 7) << 4;
  int cbuf = 0;
  for (int i = 0; i < 64; i++) {
    int nb = cbuf + 1;
    if (nb == 3) nb = 0;
    if (i + 1 < 64) produce(nb, kca, kcb);
    if (i + 2 < 64) {
      kca = *(const float4*)(cb2 + (i + 2) * 64 + pkb * 4);
      kcb = *(const float4*)(cb2 + (i + 2) * 64 + pkb * 4 + 2);
    }
    __syncthreads();
    const char* db = (const char*)sdist[cbuf];

    // S^T = (K Q^T) * c1 - slope*log2e*dist ; lane holds q=c, kv=16t+4g+r
    float s[4][4];
#pragma unroll
    for (int t = 0; t < 4; t++) {
      f32x4 sa = (f32x4){0.f, 0.f, 0.f, 0.f};
      sa = __builtin_amdgcn_mfma_f32_16x16x32_bf16(kf[t][0], aq[0], sa, 0, 0, 0);
      sa = __builtin_amdgcn_mfma_f32_16x16x32_bf16(kf[t][1], aq[1], sa, 0, 0, 0);
      f32x4 dv =
          *(const f32x4*)(db + c * 256 + ((16 * (4 * t + g)) ^ ((c & 7) << 4)));
#pragma unroll
      for (int r = 0; r < 4; r++)
        s[t][r] = __builtin_fmaf(sa[r], c1, dv[r] * negsl2);
    }
    if (i + 1 < 64) LOADK((i + 1) * 64);

    // deferred online max (THR=8 base-2); row q=c lives on 4 g-lanes
    float lm = fmaxf(fmaxf(fmaxf(s[0][0], s[0][1]), fmaxf(s[0][2], s[0][3])),
                     fmaxf(fmaxf(s[1][0], s[1][1]), fmaxf(s[1][2], s[1][3])));
    lm = fmaxf(lm,
               fmaxf(fmaxf(fmaxf(s[2][0], s[2][1]), fmaxf(s[2][2], s[2][3])),
                     fmaxf(fmaxf(s[3][0], s[3][1]), fmaxf(s[3][2], s[3][3]))));
    lm = fmaxf(lm, __shfl_xor(lm, 16));
    lm = fmaxf(lm, __shfl_xor(lm, 32));
    if (__any(lm > m2 + 8.f)) {
      float nm = fmaxf(m2, lm);
      float sc = __builtin_amdgcn_exp2f(m2 - nm);
      m2 = nm;
      float scr[4];
#pragma unroll
      for (int r = 0; r < 4; r++)
        scr[r] = __shfl(sc, (lane & 48) | (4 * g + r));
#pragma unroll
      for (int n = 0; n < 4; n++)
#pragma unroll
        for (int r = 0; r < 4; r++) o[n][r] *= scr[r];
#pragma unroll
      for (int r = 0; r < 4; r++) osum[r] *= scr[r];
    }

    // P = exp2(s - m2): kv contiguous along r -> one b64 store per t
#pragma unroll
    for (int t = 0; t < 4; t++) {
      bf16x4 pv = {(bf16)__builtin_amdgcn_exp2f(s[t][0] - m2),
                   (bf16)__builtin_amdgcn_exp2f(s[t][1] - m2),
                   (bf16)__builtin_amdgcn_exp2f(s[t][2] - m2),
                   (bf16)__builtin_amdgcn_exp2f(s[t][3] - m2)};
      *(bf16x4*)(pw + c * 128 + ((32 * t + 8 * g) ^ pmask)) = pv;
    }
    bf16x8 pa0 = *(const bf16x8*)(pw + c * 128 + ((16 * g) ^ pmask));
    bf16x8 pa1 = *(const bf16x8*)(pw + c * 128 + ((64 + 16 * g) ^ pmask));
#pragma unroll
    for (int n = 0; n < 4; n++) {
      o[n] = __builtin_amdgcn_mfma_f32_16x16x32_bf16(pa0, vf[n][0], o[n], 0, 0, 0);
      o[n] = __builtin_amdgcn_mfma_f32_16x16x32_bf16(pa1, vf[n][1], o[n], 0, 0, 0);
    }
    osum = __builtin_amdgcn_mfma_f32_16x16x32_bf16(pa0, ones, osum, 0, 0, 0);
    osum = __builtin_amdgcn_mfma_f32_16x16x32_bf16(pa1, ones, osum, 0, 0, 0);
    if (i + 1 < 64) LOADV((i + 1) * 64);
    cbuf = nb;
  }

  // epilogue: normalize, store [b,n,d] bf16 (rows q = 4g+r)
#pragma unroll
  for (int r = 0; r < 4; r++) {
    float inv = 1.f / osum[r];
    int64_t row = (int64_t)b * 4096 + q0 + g * 4 + r;
#pragma unroll
    for (int n = 0; n < 4; n++)
      Ob[row * 512 + h * 64 + n * 16 + c] = (bf16)(o[n][r] * inv);
  }
}

// ---------------- launch ---------------------------------------------------
extern "C" void kernel_launch(void* const* d_in, const int* in_sizes, int n_in,
                              void* d_out, int out_size, void* d_ws,
                              size_t ws_size, hipStream_t stream) {
  const float* x = (const float*)d_in[0];
  const float* coords = (const float*)d_in[1];
  const float* Wq = (const float*)d_in[2];
  const float* bq = (const float*)d_in[3];
  const float* Wk = (const float*)d_in[4];
  const float* bk = (const float*)d_in[5];
  const float* Wv = (const float*)d_in[6];
  const float* bv = (const float*)d_in[7];
  const float* Wp = (const float*)d_in[8];
  const float* bp = (const float*)d_in[9];
  const float* slopes = (const float*)d_in[10];

  char* ws = (char*)d_ws;
  bf16* xb = (bf16*)(ws);
  bf16* Wt = (bf16*)(ws + 8388608);
  bf16* Wpt = (bf16*)(ws + 9961472);
  bf16* Qb = (bf16*)(ws + 10485760);
  bf16* Kb = (bf16*)(ws + 18874368);
  bf16* Vt = (bf16*)(ws + 27262976);
  bf16* Ob = (bf16*)(ws + 35651584);

  hipLaunchKernelGGL(prep_kernel, dim3(1024), dim3(256), 0, stream, x, Wq, Wk,
                     Wv, Wp, xb, Wt, Wpt);
  hipLaunchKernelGGL(qkv_gemm, dim3(12, 64), dim3(256), 0, stream, xb, Wt, bq,
                     bk, bv, Qb, Kb, Vt);
  hipLaunchKernelGGL(attn_kernel, dim3(256, 2, 2), dim3(256), 0, stream, Qb,
                     Kb, Vt, coords, slopes, Ob);
  hipLaunchKernelGGL(out_gemm, dim3(4, 64), dim3(256), 0, stream, Ob, Wpt, bp,
                     (float*)d_out);
}

// Round 5
// 566.381 us; speedup vs baseline: 1.3303x; 1.0171x over previous
//
#include <hip/hip_runtime.h>
#include <stdint.h>

typedef __bf16 bf16;
typedef __attribute__((ext_vector_type(8))) __bf16 bf16x8;
typedef __attribute__((ext_vector_type(4))) __bf16 bf16x4;
typedef __attribute__((ext_vector_type(4))) float f32x4;

#define DEVFN static __device__ __forceinline__

DEVFN void gload16(const bf16* g, char* l) {
  __builtin_amdgcn_global_load_lds(
      (const __attribute__((address_space(1))) void*)g,
      (__attribute__((address_space(3))) void*)l, 16, 0, 0);
}

DEVFN int swz(int row, int kb) { return row * 128 + (kb ^ ((row & 7) << 4)); }

// ---------------- prep: fp32 -> bf16 + weight transposes --------------------
__global__ __launch_bounds__(256) void prep_kernel(
    const float* __restrict__ x, const float* __restrict__ Wq,
    const float* __restrict__ Wk, const float* __restrict__ Wv,
    const float* __restrict__ Wp, bf16* __restrict__ xb,
    bf16* __restrict__ Wt, bf16* __restrict__ Wpt) {
  const int64_t tid = blockIdx.x * 256LL + threadIdx.x;
  const int64_t stride = (int64_t)gridDim.x * 256LL;
  for (int64_t i = tid; i < (8192LL * 512) / 4; i += stride) {
    float4 v = ((const float4*)x)[i];
    bf16x4 o = {(bf16)v.x, (bf16)v.y, (bf16)v.z, (bf16)v.w};
    ((bf16x4*)xb)[i] = o;
  }
  for (int64_t i = tid; i < 1536LL * 512; i += stride) {
    int c = (int)(i >> 9), k = (int)(i & 511);
    int wsel = c >> 9, cc = c & 511;
    const float* W = wsel == 0 ? Wq : (wsel == 1 ? Wk : Wv);
    Wt[i] = (bf16)W[k * 512 + cc];
  }
  for (int64_t i = tid; i < 512LL * 512; i += stride) {
    int c = (int)(i >> 9), k = (int)(i & 511);
    Wpt[i] = (bf16)Wp[k * 512 + c];
  }
}

// ---------------- shared 128x128 bf16 GEMM mainloop (K=512, BK=64) ----------
DEVFN void gemm_main(const bf16* __restrict__ A, const bf16* __restrict__ B,
                     int rowA0, int rowB0, char* sA, char* sB, f32x4 acc[4][4],
                     int wr, int wc, int lane, int w) {
#pragma unroll
  for (int m = 0; m < 4; m++)
#pragma unroll
    for (int n = 0; n < 4; n++) acc[m][n] = (f32x4){0.f, 0.f, 0.f, 0.f};
  const int lr = lane >> 3;
  const int kswz = 8 * ((lane & 7) ^ lr);
  for (int k0 = 0; k0 < 512; k0 += 64) {
#pragma unroll
    for (int j = 0; j < 4; j++) {
      const int c = w * 4 + j;
      gload16(A + (rowA0 + c * 8 + lr) * 512 + k0 + kswz, sA + c * 1024);
      gload16(B + (rowB0 + c * 8 + lr) * 512 + k0 + kswz, sB + c * 1024);
    }
    __syncthreads();
    bf16x8 af[4][2], bfv[4][2];
#pragma unroll
    for (int m = 0; m < 4; m++)
#pragma unroll
      for (int kk = 0; kk < 2; kk++) {
        af[m][kk] = *(const bf16x8*)(sA + swz(wr * 64 + m * 16 + (lane & 15),
                                              kk * 64 + (lane >> 4) * 16));
        bfv[m][kk] = *(const bf16x8*)(sB + swz(wc * 64 + m * 16 + (lane & 15),
                                               kk * 64 + (lane >> 4) * 16));
      }
#pragma unroll
    for (int m = 0; m < 4; m++)
#pragma unroll
      for (int n = 0; n < 4; n++)
#pragma unroll
        for (int kk = 0; kk < 2; kk++)
          acc[m][n] = __builtin_amdgcn_mfma_f32_16x16x32_bf16(
              af[m][kk], bfv[n][kk], acc[m][n], 0, 0, 0);
    __syncthreads();
  }
}

// ---------------- QKV projection ------------------------------------------
__global__ __launch_bounds__(256) void qkv_gemm(
    const bf16* __restrict__ xb, const bf16* __restrict__ Wt,
    const float* __restrict__ bq, const float* __restrict__ bk,
    const float* __restrict__ bv, bf16* __restrict__ Qb, bf16* __restrict__ Kb,
    bf16* __restrict__ Vt) {
  __shared__ __align__(128) char sA[16384];
  __shared__ __align__(128) char sB[16384];
  const int lane = threadIdx.x & 63, w = threadIdx.x >> 6;
  const int wr = w >> 1, wc = w & 1;
  const int rowA0 = blockIdx.y * 128;
  const int colB0 = blockIdx.x * 128;
  f32x4 acc[4][4];
  gemm_main(xb, Wt, rowA0, colB0, sA, sB, acc, wr, wc, lane, w);
  const int which = colB0 >> 9;
  const int cc0 = colB0 & 511;
  const float* bias = which == 0 ? bq : (which == 1 ? bk : bv);
#pragma unroll
  for (int m = 0; m < 4; m++)
#pragma unroll
    for (int n = 0; n < 4; n++)
#pragma unroll
      for (int r = 0; r < 4; r++) {
        int row = rowA0 + wr * 64 + m * 16 + (lane >> 4) * 4 + r;
        int col = cc0 + wc * 64 + n * 16 + (lane & 15);
        float v = acc[m][n][r] + bias[col];
        if (which == 0) {
          Qb[(int64_t)row * 512 + col] = (bf16)v;
        } else if (which == 1) {
          Kb[(int64_t)row * 512 + col] = (bf16)v;
        } else {
          int b = row >> 12, nn = row & 4095;
          int hh = col >> 6, e = col & 63;
          Vt[(((int64_t)(b * 8 + hh)) * 64 + e) * 4096 + nn] = (bf16)v;
        }
      }
}

// ---------------- output projection (fp32 out) ----------------------------
__global__ __launch_bounds__(256) void out_gemm(const bf16* __restrict__ Ob,
                                                const bf16* __restrict__ Wpt,
                                                const float* __restrict__ bp,
                                                float* __restrict__ out) {
  __shared__ __align__(128) char sA[16384];
  __shared__ __align__(128) char sB[16384];
  const int lane = threadIdx.x & 63, w = threadIdx.x >> 6;
  const int wr = w >> 1, wc = w & 1;
  const int rowA0 = blockIdx.y * 128;
  const int colB0 = blockIdx.x * 128;
  f32x4 acc[4][4];
  gemm_main(Ob, Wpt, rowA0, colB0, sA, sB, acc, wr, wc, lane, w);
#pragma unroll
  for (int m = 0; m < 4; m++)
#pragma unroll
    for (int n = 0; n < 4; n++)
#pragma unroll
      for (int r = 0; r < 4; r++) {
        int row = rowA0 + wr * 64 + m * 16 + (lane >> 4) * 4 + r;
        int col = colB0 + wc * 64 + n * 16 + (lane & 15);
        out[(int64_t)row * 512 + col] = acc[m][n][r] + bp[col];
      }
}

// ---------------- fused flash attention, barrier-free swapped-QK^T ---------
// grid 1024 flat (XCD-aware decode), 256 thr = 4 fully independent waves
// (no __syncthreads anywhere). Wave = one head, 16 q-rows. Lane owns q-row
// q0+(lane&15); bias dist computed in-register from L1-broadcast coords.
__global__ __launch_bounds__(256) void attn_kernel(
    const bf16* __restrict__ Qb, const bf16* __restrict__ Kb,
    const bf16* __restrict__ Vt, const float* __restrict__ coords,
    const float* __restrict__ slopes, bf16* __restrict__ Ob) {
  __shared__ __align__(128) char sP[4][2048];  // per-wave P tile, wave-private

  const int tid = threadIdx.x;
  const int lane = tid & 63, w = tid >> 6;
  const int c = lane & 15, g = lane >> 4;

  // XCD-aware decode: XCD pair {2k,2k+1} serves one (b,hg) combo (4MB K+V=L2)
  const int id = blockIdx.x;          // 0..1023
  const int xcd = id & 7, j = id >> 3;
  const int combo = xcd >> 1;         // 0..3
  const int b = combo >> 1, hg = combo & 1;
  const int qt = j | ((xcd & 1) << 7);  // 0..255
  const int q0 = qt * 16;
  const int h = hg * 4 + w;

  const float LOG2E = 1.4426950408889634f;
  const float c1 = 0.125f * LOG2E;
  const float negsl2 = -slopes[h] * LOG2E;

  // Q fragments (B-operand of swapped QK^T): lane holds Q[q=c][hd=g*8+j]
  bf16x8 aq[2];
  {
    int64_t base = ((int64_t)(b * 4096 + q0 + c)) * 512 + h * 64 + g * 8;
    aq[0] = *(const bf16x8*)(Qb + base);
    aq[1] = *(const bf16x8*)(Qb + base + 32);
  }
  const float2* cb2 = (const float2*)coords + (int64_t)b * 4096;
  float qcx, qcy;
  {
    float2 qc = cb2[q0 + c];
    qcx = qc.x;
    qcy = qc.y;
  }

  bf16x8 ones;
#pragma unroll
  for (int jj = 0; jj < 8; jj++) ones[jj] = (bf16)1.0f;

  float m2 = -1e30f;  // running max for q=c (one row per lane)
  f32x4 o[4], osum;
#pragma unroll
  for (int n = 0; n < 4; n++) o[n] = (f32x4){0.f, 0.f, 0.f, 0.f};
  osum = (f32x4){0.f, 0.f, 0.f, 0.f};

  const bf16* Kp = Kb + (int64_t)b * 4096 * 512 + h * 64;
  const bf16* Vp = Vt + (int64_t)(b * 8 + h) * 64 * 4096;

  bf16x8 kf[4][2], vf[4][2];
#define LOADK(KV)                                                         \
  {                                                                       \
    _Pragma("unroll") for (int t = 0; t < 4; t++) _Pragma("unroll") for ( \
        int kk = 0; kk < 2; kk++) kf[t][kk] =                             \
        *(const bf16x8*)(Kp + (int)(((KV) + t * 16 + c) * 512 +           \
                                    kk * 32 + g * 8));                    \
  }
#define LOADV(KV)                                                         \
  {                                                                       \
    _Pragma("unroll") for (int n = 0; n < 4; n++) _Pragma("unroll") for ( \
        int kk = 0; kk < 2; kk++) vf[n][kk] =                             \
        *(const bf16x8*)(Vp + (int)((n * 16 + c) * 4096 + (KV) +          \
                                    kk * 32 + g * 8));                    \
  }

  LOADK(0);
  LOADV(0);

  char* pw = (char*)sP[w];
  const int pmask = (c & 7) << 4;
  for (int i = 0; i < 64; i++) {
    const int kvb = i * 64;

    // S^T = (K Q^T): lane holds q=c, kv=16t+4g+r
    float s[4][4];
#pragma unroll
    for (int t = 0; t < 4; t++) {
      f32x4 sa = (f32x4){0.f, 0.f, 0.f, 0.f};
      sa = __builtin_amdgcn_mfma_f32_16x16x32_bf16(kf[t][0], aq[0], sa, 0, 0, 0);
      sa = __builtin_amdgcn_mfma_f32_16x16x32_bf16(kf[t][1], aq[1], sa, 0, 0, 0);
#pragma unroll
      for (int r = 0; r < 4; r++) s[t][r] = sa[r];
    }
    if (i + 1 < 64) LOADK((i + 1) * 64);

    // in-register bias: dist(q=c, kv) from L1-broadcast coords (paired t to
    // bound VGPR)
#pragma unroll
    for (int tp = 0; tp < 2; tp++) {
      float4 A0 = *(const float4*)(cb2 + kvb + (2 * tp) * 16 + g * 4);
      float4 A1 = *(const float4*)(cb2 + kvb + (2 * tp) * 16 + g * 4 + 2);
      float4 B0 = *(const float4*)(cb2 + kvb + (2 * tp + 1) * 16 + g * 4);
      float4 B1 = *(const float4*)(cb2 + kvb + (2 * tp + 1) * 16 + g * 4 + 2);
      float dx, dy;
#define DIST1(T, R, CX, CY)                                             \
  dx = qcx - (CX);                                                      \
  dy = qcy - (CY);                                                      \
  s[T][R] = __builtin_fmaf(s[T][R], c1,                                 \
                           __builtin_amdgcn_sqrtf(dx * dx + dy * dy) *  \
                               negsl2);
      DIST1(2 * tp, 0, A0.x, A0.y)
      DIST1(2 * tp, 1, A0.z, A0.w)
      DIST1(2 * tp, 2, A1.x, A1.y)
      DIST1(2 * tp, 3, A1.z, A1.w)
      DIST1(2 * tp + 1, 0, B0.x, B0.y)
      DIST1(2 * tp + 1, 1, B0.z, B0.w)
      DIST1(2 * tp + 1, 2, B1.x, B1.y)
      DIST1(2 * tp + 1, 3, B1.z, B1.w)
#undef DIST1
    }

    // deferred online max (THR=8 base-2); row q=c lives on 4 g-lanes
    float lm = fmaxf(fmaxf(fmaxf(s[0][0], s[0][1]), fmaxf(s[0][2], s[0][3])),
                     fmaxf(fmaxf(s[1][0], s[1][1]), fmaxf(s[1][2], s[1][3])));
    lm = fmaxf(lm,
               fmaxf(fmaxf(fmaxf(s[2][0], s[2][1]), fmaxf(s[2][2], s[2][3])),
                     fmaxf(fmaxf(s[3][0], s[3][1]), fmaxf(s[3][2], s[3][3]))));
    lm = fmaxf(lm, __shfl_xor(lm, 16));
    lm = fmaxf(lm, __shfl_xor(lm, 32));
    if (__any(lm > m2 + 8.f)) {
      float nm = fmaxf(m2, lm);
      float sc = __builtin_amdgcn_exp2f(m2 - nm);
      m2 = nm;
      float scr[4];
#pragma unroll
      for (int r = 0; r < 4; r++)
        scr[r] = __shfl(sc, (lane & 48) | (4 * g + r));
#pragma unroll
      for (int n = 0; n < 4; n++)
#pragma unroll
        for (int r = 0; r < 4; r++) o[n][r] *= scr[r];
#pragma unroll
      for (int r = 0; r < 4; r++) osum[r] *= scr[r];
    }

    // P = exp2(s - m2): kv contiguous along r -> one b64 store per t
#pragma unroll
    for (int t = 0; t < 4; t++) {
      bf16x4 pv = {(bf16)__builtin_amdgcn_exp2f(s[t][0] - m2),
                   (bf16)__builtin_amdgcn_exp2f(s[t][1] - m2),
                   (bf16)__builtin_amdgcn_exp2f(s[t][2] - m2),
                   (bf16)__builtin_amdgcn_exp2f(s[t][3] - m2)};
      *(bf16x4*)(pw + c * 128 + ((32 * t + 8 * g) ^ pmask)) = pv;
    }
    bf16x8 pa0 = *(const bf16x8*)(pw + c * 128 + ((16 * g) ^ pmask));
    bf16x8 pa1 = *(const bf16x8*)(pw + c * 128 + ((64 + 16 * g) ^ pmask));
#pragma unroll
    for (int n = 0; n < 4; n++) {
      o[n] = __builtin_amdgcn_mfma_f32_16x16x32_bf16(pa0, vf[n][0], o[n], 0, 0, 0);
      o[n] = __builtin_amdgcn_mfma_f32_16x16x32_bf16(pa1, vf[n][1], o[n], 0, 0, 0);
    }
    osum = __builtin_amdgcn_mfma_f32_16x16x32_bf16(pa0, ones, osum, 0, 0, 0);
    osum = __builtin_amdgcn_mfma_f32_16x16x32_bf16(pa1, ones, osum, 0, 0, 0);
    if (i + 1 < 64) LOADV((i + 1) * 64);
  }

  // epilogue: normalize, store [b,n,d] bf16 (rows q = 4g+r)
#pragma unroll
  for (int r = 0; r < 4; r++) {
    float inv = 1.f / osum[r];
    int64_t row = (int64_t)b * 4096 + q0 + g * 4 + r;
#pragma unroll
    for (int n = 0; n < 4; n++)
      Ob[row * 512 + h * 64 + n * 16 + c] = (bf16)(o[n][r] * inv);
  }
}

// ---------------- launch ---------------------------------------------------
extern "C" void kernel_launch(void* const* d_in, const int* in_sizes, int n_in,
                              void* d_out, int out_size, void* d_ws,
                              size_t ws_size, hipStream_t stream) {
  const float* x = (const float*)d_in[0];
  const float* coords = (const float*)d_in[1];
  const float* Wq = (const float*)d_in[2];
  const float* bq = (const float*)d_in[3];
  const float* Wk = (const float*)d_in[4];
  const float* bk = (const float*)d_in[5];
  const float* Wv = (const float*)d_in[6];
  const float* bv = (const float*)d_in[7];
  const float* Wp = (const float*)d_in[8];
  const float* bp = (const float*)d_in[9];
  const float* slopes = (const float*)d_in[10];

  char* ws = (char*)d_ws;
  bf16* xb = (bf16*)(ws);
  bf16* Wt = (bf16*)(ws + 8388608);
  bf16* Wpt = (bf16*)(ws + 9961472);
  bf16* Qb = (bf16*)(ws + 10485760);
  bf16* Kb = (bf16*)(ws + 18874368);
  bf16* Vt = (bf16*)(ws + 27262976);
  bf16* Ob = (bf16*)(ws + 35651584);

  hipLaunchKernelGGL(prep_kernel, dim3(1024), dim3(256), 0, stream, x, Wq, Wk,
                     Wv, Wp, xb, Wt, Wpt);
  hipLaunchKernelGGL(qkv_gemm, dim3(12, 64), dim3(256), 0, stream, xb, Wt, bq,
                     bk, bv, Qb, Kb, Vt);
  hipLaunchKernelGGL(attn_kernel, dim3(1024), dim3(256), 0, stream, Qb, Kb,
                     Vt, coords, slopes, Ob);
  hipLaunchKernelGGL(out_gemm, dim3(4, 64), dim3(256), 0, stream, Ob, Wpt, bp,
                     (float*)d_out);
}